// Round 1
// baseline (87.887 us; speedup 1.0000x reference)
//
#include <hip/hip_runtime.h>

// Problem constants (from reference): x:(8,64,56,56) f32, k=7, s=1, p=3, d=1
// out:(8,64,49,3136) f32.  out[n,c,ki*7+kj, oh*56+ow] =
//   x[n,c,oh,ow] - (in-bounds ? x[n,c,oh+ki-3, ow+kj-3] : 0)

constexpr int N_ = 8, C_ = 64, H_ = 56, W_ = 56;
constexpr int K_ = 7, P_ = 3;
constexpr int KK_ = K_ * K_;           // 49
constexpr int OHW_ = H_ * W_;          // 3136
constexpr int V4_PER_ROW = OHW_ / 4;   // 784
constexpr int ROWS = N_ * C_ * KK_;    // 25088
constexpr int TOTAL_V4 = ROWS * V4_PER_ROW;  // 19,668,992 (< 2^31)

typedef float f32x4 __attribute__((ext_vector_type(4)));

__global__ __launch_bounds__(256)
void san_kernel(const float* __restrict__ x, float* __restrict__ out) {
    int idx = blockIdx.x * blockDim.x + threadIdx.x;
    if (idx >= TOTAL_V4) return;

    int v  = idx % V4_PER_ROW;   // float4 index within (n,c,kk) row
    int r  = idx / V4_PER_ROW;   // (n*C + c)*49 + kk
    int kk = r % KK_;
    int nc = r / KK_;            // n*C + c
    int ki = kk / K_;
    int kj = kk % K_;

    int e  = v * 4;              // element offset within 3136
    int oh = e / W_;
    int ow = e % W_;             // multiple of 4 (56 % 4 == 0)

    const float* plane = x + (long long)nc * OHW_;

    // center: aligned 16B load
    f32x4 cen = *reinterpret_cast<const f32x4*>(plane + oh * W_ + ow);

    int ih = oh + ki - P_;
    f32x4 res;
    if (ih >= 0 && ih < H_) {
        const float* nrow = plane + ih * W_;
        #pragma unroll
        for (int t = 0; t < 4; ++t) {
            int iw = ow + t + kj - P_;
            float nb = (iw >= 0 && iw < W_) ? nrow[iw] : 0.0f;
            res[t] = cen[t] - nb;
        }
    } else {
        res = cen;               // neighbor row fully out of bounds -> zero pad
    }

    __builtin_nontemporal_store(res, reinterpret_cast<f32x4*>(out) + idx);
}

extern "C" void kernel_launch(void* const* d_in, const int* in_sizes, int n_in,
                              void* d_out, int out_size, void* d_ws, size_t ws_size,
                              hipStream_t stream) {
    const float* x = (const float*)d_in[0];
    float* out = (float*)d_out;
    int blocks = (TOTAL_V4 + 255) / 256;
    san_kernel<<<blocks, 256, 0, stream>>>(x, out);
}

// Round 2
// 67.162 us; speedup vs baseline: 1.3086x; 1.3086x over previous
//
#include <hip/hip_runtime.h>

// x:(8,64,56,56) f32 -> out:(8,64,49,3136) f32
// out[n,c,ki*7+kj, oh*56+ow] = x[n,c,oh,ow] - (in-bounds ? x[n,c,oh+ki-3,ow+kj-3] : 0)
//
// Strategy: one thread per 4-wide output strip (oh, ow..ow+3) of one (n,c) plane.
// Keep the 7x12 input window in registers (21 predicated float4 loads, all
// compile-time indexed), then emit all 49 nontemporal float4 stores.
// Write-stream bound: 314.7 MB out, ceiling ~6.9 TB/s (measured fillBuffer).

constexpr int N_ = 8, C_ = 64, H_ = 56, W_ = 56;
constexpr int K_ = 7, P_ = 3;
constexpr int KK_  = K_ * K_;        // 49
constexpr int OHW_ = H_ * W_;        // 3136
constexpr int O4_  = W_ / 4;         // 14 float4s per row
constexpr int POS4_ = N_ * C_ * H_ * O4_;  // 401408 threads (divisible by 256)

typedef float f32x4 __attribute__((ext_vector_type(4)));

__global__ __launch_bounds__(256)
void san_kernel(const float* __restrict__ x, float* __restrict__ out) {
    int idx = blockIdx.x * 256 + threadIdx.x;   // POS4_ % 256 == 0, no tail check

    int o4 = idx % O4_;          // float4 column index
    int t1 = idx / O4_;
    int oh = t1 % H_;
    int nc = t1 / H_;            // n*C + c
    int ow = o4 * 4;

    const float* plane = x + (size_t)nc * OHW_;

    // Register window: rows oh-3..oh+3, cols ow-4..ow+7 (zero outside plane).
    float win[K_][12];
    #pragma unroll
    for (int di = 0; di < K_; ++di) {
        int r = oh + di - P_;
        bool rv = (unsigned)r < (unsigned)H_;
        #pragma unroll
        for (int q = 0; q < 3; ++q) {
            int c = ow + 4 * q - 4;              // -4, 0, +4 relative to ow
            f32x4 v = {0.f, 0.f, 0.f, 0.f};
            if (rv && (unsigned)c < (unsigned)W_) {
                v = *reinterpret_cast<const f32x4*>(plane + r * W_ + c);
            }
            win[di][4 * q + 0] = v[0];
            win[di][4 * q + 1] = v[1];
            win[di][4 * q + 2] = v[2];
            win[di][4 * q + 3] = v[3];
        }
    }

    // Center = window row 3, cols 4..7.
    float cen0 = win[P_][4], cen1 = win[P_][5], cen2 = win[P_][6], cen3 = win[P_][7];

    float* op = out + (size_t)nc * KK_ * OHW_ + oh * W_ + ow;

    #pragma unroll
    for (int ki = 0; ki < K_; ++ki) {
        #pragma unroll
        for (int kj = 0; kj < K_; ++kj) {
            // neighbor col (ow+t+kj-3) -> window col (t + kj + 1)
            f32x4 res;
            res[0] = cen0 - win[ki][kj + 1];
            res[1] = cen1 - win[ki][kj + 2];
            res[2] = cen2 - win[ki][kj + 3];
            res[3] = cen3 - win[ki][kj + 4];
            __builtin_nontemporal_store(res, reinterpret_cast<f32x4*>(op));
            op += OHW_;
        }
    }
}

extern "C" void kernel_launch(void* const* d_in, const int* in_sizes, int n_in,
                              void* d_out, int out_size, void* d_ws, size_t ws_size,
                              hipStream_t stream) {
    const float* x = (const float*)d_in[0];
    float* out = (float*)d_out;
    san_kernel<<<POS4_ / 256, 256, 0, stream>>>(x, out);
}

// Round 3
// 59.085 us; speedup vs baseline: 1.4875x; 1.1367x over previous
//
#include <hip/hip_runtime.h>

// x:(8,64,56,56) f32 -> out:(8,64,49,3136) f32
// out[n,c,ki*7+kj, oh*56+ow] = x[n,c,oh,ow] - (in-bounds ? x[n,c,oh+ki-3,ow+kj-3] : 0)
//
// R2: identical to R1 except regular (cached) stores instead of
// __builtin_nontemporal_store — A/B test of the write-path theory.

constexpr int N_ = 8, C_ = 64, H_ = 56, W_ = 56;
constexpr int K_ = 7, P_ = 3;
constexpr int KK_  = K_ * K_;        // 49
constexpr int OHW_ = H_ * W_;        // 3136
constexpr int O4_  = W_ / 4;         // 14 float4s per row
constexpr int POS4_ = N_ * C_ * H_ * O4_;  // 401408 threads (divisible by 256)

typedef float f32x4 __attribute__((ext_vector_type(4)));

__global__ __launch_bounds__(256)
void san_kernel(const float* __restrict__ x, float* __restrict__ out) {
    int idx = blockIdx.x * 256 + threadIdx.x;   // POS4_ % 256 == 0, no tail check

    int o4 = idx % O4_;          // float4 column index
    int t1 = idx / O4_;
    int oh = t1 % H_;
    int nc = t1 / H_;            // n*C + c
    int ow = o4 * 4;

    const float* plane = x + (size_t)nc * OHW_;

    // Register window: rows oh-3..oh+3, cols ow-4..ow+7 (zero outside plane).
    float win[K_][12];
    #pragma unroll
    for (int di = 0; di < K_; ++di) {
        int r = oh + di - P_;
        bool rv = (unsigned)r < (unsigned)H_;
        #pragma unroll
        for (int q = 0; q < 3; ++q) {
            int c = ow + 4 * q - 4;              // -4, 0, +4 relative to ow
            f32x4 v = {0.f, 0.f, 0.f, 0.f};
            if (rv && (unsigned)c < (unsigned)W_) {
                v = *reinterpret_cast<const f32x4*>(plane + r * W_ + c);
            }
            win[di][4 * q + 0] = v[0];
            win[di][4 * q + 1] = v[1];
            win[di][4 * q + 2] = v[2];
            win[di][4 * q + 3] = v[3];
        }
    }

    // Center = window row 3, cols 4..7.
    float cen0 = win[P_][4], cen1 = win[P_][5], cen2 = win[P_][6], cen3 = win[P_][7];

    float* op = out + (size_t)nc * KK_ * OHW_ + oh * W_ + ow;

    #pragma unroll
    for (int ki = 0; ki < K_; ++ki) {
        #pragma unroll
        for (int kj = 0; kj < K_; ++kj) {
            // neighbor col (ow+t+kj-3) -> window col (t + kj + 1)
            f32x4 res;
            res[0] = cen0 - win[ki][kj + 1];
            res[1] = cen1 - win[ki][kj + 2];
            res[2] = cen2 - win[ki][kj + 3];
            res[3] = cen3 - win[ki][kj + 4];
            *reinterpret_cast<f32x4*>(op) = res;   // regular cached store
            op += OHW_;
        }
    }
}

extern "C" void kernel_launch(void* const* d_in, const int* in_sizes, int n_in,
                              void* d_out, int out_size, void* d_ws, size_t ws_size,
                              hipStream_t stream) {
    const float* x = (const float*)d_in[0];
    float* out = (float*)d_out;
    san_kernel<<<POS4_ / 256, 256, 0, stream>>>(x, out);
}

// Round 4
// 58.220 us; speedup vs baseline: 1.5096x; 1.0149x over previous
//
#include <hip/hip_runtime.h>

// x:(8,64,56,56) f32 -> out:(8,64,49,3136) f32
// out[n,c,ki*7+kj, oh*56+ow] = x[n,c,oh,ow] - (in-bounds ? x[n,c,oh+ki-3,ow+kj-3] : 0)
//
// R3: identical math to R2 (cached stores, register window), but block=64
// (one wave per block). Grid 1568x256 was 6.125 blocks/CU -> 7/6.125 = +14%
// tail quantization; 6272x64 = 24.5 blocks/CU -> 25/24.5 = +2%.

constexpr int N_ = 8, C_ = 64, H_ = 56, W_ = 56;
constexpr int K_ = 7, P_ = 3;
constexpr int KK_  = K_ * K_;        // 49
constexpr int OHW_ = H_ * W_;        // 3136
constexpr int O4_  = W_ / 4;         // 14 float4s per row
constexpr int POS4_ = N_ * C_ * H_ * O4_;  // 401408 strips (divisible by 64)
constexpr int BLK_ = 64;

typedef float f32x4 __attribute__((ext_vector_type(4)));

__global__ __launch_bounds__(BLK_)
void san_kernel(const float* __restrict__ x, float* __restrict__ out) {
    int idx = blockIdx.x * BLK_ + threadIdx.x;   // POS4_ % 64 == 0, no tail check

    int o4 = idx % O4_;          // float4 column index
    int t1 = idx / O4_;
    int oh = t1 % H_;
    int nc = t1 / H_;            // n*C + c
    int ow = o4 * 4;

    const float* plane = x + (size_t)nc * OHW_;

    // Register window: rows oh-3..oh+3, cols ow-4..ow+7 (zero outside plane).
    float win[K_][12];
    #pragma unroll
    for (int di = 0; di < K_; ++di) {
        int r = oh + di - P_;
        bool rv = (unsigned)r < (unsigned)H_;
        #pragma unroll
        for (int q = 0; q < 3; ++q) {
            int c = ow + 4 * q - 4;              // -4, 0, +4 relative to ow
            f32x4 v = {0.f, 0.f, 0.f, 0.f};
            if (rv && (unsigned)c < (unsigned)W_) {
                v = *reinterpret_cast<const f32x4*>(plane + r * W_ + c);
            }
            win[di][4 * q + 0] = v[0];
            win[di][4 * q + 1] = v[1];
            win[di][4 * q + 2] = v[2];
            win[di][4 * q + 3] = v[3];
        }
    }

    // Center = window row 3, cols 4..7.
    float cen0 = win[P_][4], cen1 = win[P_][5], cen2 = win[P_][6], cen3 = win[P_][7];

    float* op = out + (size_t)nc * KK_ * OHW_ + oh * W_ + ow;

    #pragma unroll
    for (int ki = 0; ki < K_; ++ki) {
        #pragma unroll
        for (int kj = 0; kj < K_; ++kj) {
            // neighbor col (ow+t+kj-3) -> window col (t + kj + 1)
            f32x4 res;
            res[0] = cen0 - win[ki][kj + 1];
            res[1] = cen1 - win[ki][kj + 2];
            res[2] = cen2 - win[ki][kj + 3];
            res[3] = cen3 - win[ki][kj + 4];
            *reinterpret_cast<f32x4*>(op) = res;   // regular cached store
            op += OHW_;
        }
    }
}

extern "C" void kernel_launch(void* const* d_in, const int* in_sizes, int n_in,
                              void* d_out, int out_size, void* d_ws, size_t ws_size,
                              hipStream_t stream) {
    const float* x = (const float*)d_in[0];
    float* out = (float*)d_out;
    san_kernel<<<POS4_ / BLK_, BLK_, 0, stream>>>(x, out);
}

// Round 5
// 55.400 us; speedup vs baseline: 1.5864x; 1.0509x over previous
//
#include <hip/hip_runtime.h>

// x:(8,64,56,56) f32 -> out:(8,64,49,3136) f32
// out[n,c,ki*7+kj, oh*56+ow] = x[n,c,oh,ow] - (in-bounds ? x[n,c,oh+ki-3,ow+kj-3] : 0)
//
// R4: one block per (n,c) plane (512 blocks = 2/CU exactly). Input plane
// staged in LDS with zero halo (no bounds checks); block writes its 614 KB
// output region fully sequentially (kk-major) to maximize DRAM locality.

constexpr int H_ = 56, W_ = 56;
constexpr int KK_  = 49;
constexpr int OHW_ = 3136;              // 56*56
constexpr int PP_  = 63;                // padded LDS pitch (floats); 63 % 32 = 31 -> low conflicts
constexpr int PR_  = 62;                // padded rows: -3..58
constexpr int NC_  = 512;               // 8*64 planes
constexpr int LDSN_ = PR_ * PP_;        // 3906 floats = 15.6 KB

typedef float f32x4 __attribute__((ext_vector_type(4)));

__global__ __launch_bounds__(256)
void san_kernel(const float* __restrict__ x, float* __restrict__ out) {
    __shared__ float lds[LDSN_];
    const int nc = blockIdx.x;
    const int t  = threadIdx.x;

    // 1) zero padded plane (halo stays zero -> OOB neighbors read 0)
    #pragma unroll
    for (int i = 0; i < 16; ++i) {
        int j = t + 256 * i;
        if (j < LDSN_) lds[j] = 0.0f;
    }
    __syncthreads();

    const float* plane = x + (size_t)nc * OHW_;

    // 2) stage interior; keep each slot's center f4 + LDS base in registers.
    //    slot S covers f4-index e4 = t + 256*S of the plane (784 f4 total).
    f32x4 cen0{}, cen1{}, cen2{}, cen3{};
    int ab0 = 0, ab1 = 0, ab2 = 0, ab3 = 0;
    const bool has3 = (t < 16);          // 784 - 3*256 = 16

#define STAGE(S, CEN, AB)                                           \
    {                                                               \
        int e4 = t + 256 * (S);                                     \
        int oh = e4 / 14, o4 = e4 - oh * 14;                        \
        CEN = *reinterpret_cast<const f32x4*>(plane + e4 * 4);      \
        int lb = (oh + 3) * PP_ + o4 * 4 + 3;                       \
        lds[lb + 0] = CEN[0]; lds[lb + 1] = CEN[1];                 \
        lds[lb + 2] = CEN[2]; lds[lb + 3] = CEN[3];                 \
        AB = oh * PP_ + o4 * 4;                                     \
    }
    STAGE(0, cen0, ab0)
    STAGE(1, cen1, ab1)
    STAGE(2, cen2, ab2)
    if (has3) STAGE(3, cen3, ab3)
#undef STAGE
    __syncthreads();

    // 3) kk-major sweep: block writes its 49*12544 B region front-to-back.
    //    neighbor(padded) = ab + ki*PP_ + kj + tt  (compile-time imm offsets)
    float* ob  = out + (size_t)nc * (KK_ * OHW_);
    float* op0 = ob + (size_t)(t      ) * 4;
    float* op1 = ob + (size_t)(t + 256) * 4;
    float* op2 = ob + (size_t)(t + 512) * 4;

    #pragma unroll
    for (int ki = 0; ki < 7; ++ki) {
        #pragma unroll
        for (int kj = 0; kj < 7; ++kj) {
            const int off = ki * PP_ + kj;
            f32x4 r0, r1, r2;
            #pragma unroll
            for (int tt = 0; tt < 4; ++tt) {
                r0[tt] = cen0[tt] - lds[ab0 + off + tt];
                r1[tt] = cen1[tt] - lds[ab1 + off + tt];
                r2[tt] = cen2[tt] - lds[ab2 + off + tt];
            }
            *reinterpret_cast<f32x4*>(op0) = r0;  op0 += OHW_;
            *reinterpret_cast<f32x4*>(op1) = r1;  op1 += OHW_;
            *reinterpret_cast<f32x4*>(op2) = r2;  op2 += OHW_;
        }
    }

    // 4) tail slot (16 threads): e4 = 768 + t
    if (has3) {
        float* op3 = ob + (size_t)(t + 768) * 4;
        for (int ki = 0; ki < 7; ++ki) {
            for (int kj = 0; kj < 7; ++kj) {
                int off = ki * PP_ + kj;
                f32x4 r;
                #pragma unroll
                for (int tt = 0; tt < 4; ++tt)
                    r[tt] = cen3[tt] - lds[ab3 + off + tt];
                *reinterpret_cast<f32x4*>(op3) = r;  op3 += OHW_;
            }
        }
    }
}

extern "C" void kernel_launch(void* const* d_in, const int* in_sizes, int n_in,
                              void* d_out, int out_size, void* d_ws, size_t ws_size,
                              hipStream_t stream) {
    const float* x = (const float*)d_in[0];
    float* out = (float*)d_out;
    san_kernel<<<NC_, 256, 0, stream>>>(x, out);
}